// Round 4
// baseline (393.681 us; speedup 1.0000x reference)
//
#include <hip/hip_runtime.h>
#include <math.h>

#define HH 1024
#define SS 1024
#define EE 3

typedef __bf16 bf16x8 __attribute__((ext_vector_type(8)));
typedef float floatx4 __attribute__((ext_vector_type(4)));

__device__ __forceinline__ unsigned short f2bf(float f) {
  union { float f; unsigned u; } v; v.f = f;
  unsigned r = 0x7FFFu + ((v.u >> 16) & 1u);
  return (unsigned short)((v.u + r) >> 16);
}

__device__ __forceinline__ unsigned pack2(float lo, float hi) {
#if __has_builtin(__builtin_amdgcn_cvt_pk_bf16_f32)
  auto p = __builtin_amdgcn_cvt_pk_bf16_f32(lo, hi);
  return __builtin_bit_cast(unsigned, p);
#else
  return ((unsigned)f2bf(hi) << 16) | (unsigned)f2bf(lo);
#endif
}

// ---------------- kernel 1: routing (logits -> argmax, gate) ----------------
// Wave-per-branch partition; gate weights hoisted to registers once per wave;
// grid-stride over tokens (2048 waves per branch).
__global__ __launch_bounds__(256) void k_route(
    const float* __restrict__ x,    // [B,3,S,H] fp32
    const float* __restrict__ wg,   // [3,H,3]   fp32
    int* __restrict__ idx_out,      // [3*T]
    float* __restrict__ gv_out,     // [3*T]
    int T) {
  int gw = (blockIdx.x * 256 + threadIdx.x) >> 6;  // global wave id [0,6144)
  int lane = threadIdx.x & 63;
  int r = gw >> 11;          // branch [0,3)
  int t0 = gw & 2047;        // starting token
  const float* w = wg + (size_t)r * HH * EE;

  // hoist this lane's gate slice: chunks c=0,1; h0 = c*512 + lane*8; 24 floats each
  float wreg[2][24];
#pragma unroll
  for (int c = 0; c < 2; ++c) {
    int h0 = c * 512 + lane * 8;
    const float4* wp = reinterpret_cast<const float4*>(w + (size_t)h0 * 3);
#pragma unroll
    for (int j = 0; j < 6; ++j)
      *reinterpret_cast<float4*>(&wreg[c][4 * j]) = wp[j];
  }

  for (int t = t0; t < T; t += 2048) {
    const float* xrow =
        x + (size_t)(((t >> 10) * 3 + r) * SS + (t & 1023)) * HH;
    double a0 = 0, a1 = 0, a2 = 0;
#pragma unroll
    for (int c = 0; c < 2; ++c) {
      int h0 = c * 512 + lane * 8;
      float4 xa = *reinterpret_cast<const float4*>(xrow + h0);
      float4 xb = *reinterpret_cast<const float4*>(xrow + h0 + 4);
      float xs[8] = {xa.x, xa.y, xa.z, xa.w, xb.x, xb.y, xb.z, xb.w};
#pragma unroll
      for (int j = 0; j < 8; ++j) {
        double xv = (double)xs[j];
        a0 += xv * (double)wreg[c][3 * j + 0];
        a1 += xv * (double)wreg[c][3 * j + 1];
        a2 += xv * (double)wreg[c][3 * j + 2];
      }
    }
#pragma unroll
    for (int d = 32; d >= 1; d >>= 1) {
      a0 += __shfl_xor(a0, d, 64);
      a1 += __shfl_xor(a1, d, 64);
      a2 += __shfl_xor(a2, d, 64);
    }
    if (lane == 0) {
      int best = 0; double bl = a0;
      if (a1 > bl) { best = 1; bl = a1; }  // strict >: first-max wins
      if (a2 > bl) { best = 2; bl = a2; }
      float g = 1.0f / (expf((float)(a0 - bl)) + expf((float)(a1 - bl)) +
                        expf((float)(a2 - bl)));
      idx_out[r * T + t] = best;
      gv_out[r * T + t] = g;
    }
  }
}

// ---------------- kernel 2: arrival-order scan + expert lists ----------------
__global__ __launch_bounds__(1024) void k_scan(
    const int* __restrict__ idx, const float* __restrict__ gv,
    int* __restrict__ perm,    // [3*3*T] token ids per (branch,expert), arrival order
    float* __restrict__ scale, // [3*T]  gate*keep (0 if dropped)
    int* __restrict__ counts,  // [9]
    int T, int C) {
  int r = blockIdx.x;
  int tid = threadIdx.x;
  int per = T >> 10;  // tokens per thread (T=8192 -> 8)
  int t0 = tid * per;
  const int* idxr = idx + (size_t)r * T;

  int c0 = 0, c1 = 0, c2 = 0;
  for (int k = 0; k < per; ++k) {
    int e = idxr[t0 + k];
    c0 += (e == 0); c1 += (e == 1); c2 += (e == 2);
  }
  int lane = tid & 63, wv = tid >> 6;
  int s0 = c0, s1 = c1, s2 = c2;  // wave inclusive scan
  for (int d = 1; d < 64; d <<= 1) {
    int u0 = __shfl_up(s0, d, 64);
    int u1 = __shfl_up(s1, d, 64);
    int u2 = __shfl_up(s2, d, 64);
    if (lane >= d) { s0 += u0; s1 += u1; s2 += u2; }
  }
  __shared__ int wsum[16][3];
  __shared__ int wbase[16][3];
  if (lane == 63) { wsum[wv][0] = s0; wsum[wv][1] = s1; wsum[wv][2] = s2; }
  __syncthreads();
  if (tid == 0) {
    int b0 = 0, b1 = 0, b2 = 0;
    int nw = blockDim.x >> 6;
    for (int i = 0; i < nw; ++i) {
      wbase[i][0] = b0; wbase[i][1] = b1; wbase[i][2] = b2;
      b0 += wsum[i][0]; b1 += wsum[i][1]; b2 += wsum[i][2];
    }
    counts[r * 3 + 0] = b0; counts[r * 3 + 1] = b1; counts[r * 3 + 2] = b2;
  }
  __syncthreads();
  int off[3];
  off[0] = wbase[wv][0] + s0 - c0;
  off[1] = wbase[wv][1] + s1 - c1;
  off[2] = wbase[wv][2] + s2 - c2;
  for (int k = 0; k < per; ++k) {
    int e = idxr[t0 + k];
    int p = off[e]++;
    perm[(size_t)(r * 3 + e) * T + p] = t0 + k;
    scale[(size_t)r * T + t0 + k] = (p < C) ? gv[(size_t)r * T + t0 + k] : 0.0f;
  }
}

// ---------------- kernel 3: grouped GEMM (gathered A rows) ----------------
// fp32 global -> bf16 LDS, 128x128 tile, BK=32, 4 waves (2x2 of 64x64),
// double-buffered LDS, ONE barrier per K-iter, loads software-pipelined.
__global__ __launch_bounds__(256) void k_gemm(
    const float* __restrict__ x,    // [B,3,S,H]
    const float* __restrict__ We,   // [3,3,H,H] (out-major: W[o][h])
    const float* __restrict__ be,   // [3,3,H]
    const int* __restrict__ perm, const float* __restrict__ scale,
    const int* __restrict__ counts,
    float* __restrict__ out,        // [B,3,S,H]
    int T) {
  int z = blockIdx.z;           // r*3+e
  int r = z / 3;
  int count = counts[z];
  int m0 = blockIdx.x * 128;    // m is fast-varying -> B-slice L2 locality
  if (m0 >= count) return;
  int n0 = blockIdx.y * 128;

  __shared__ alignas(16) unsigned short As[2][128 * 32];
  __shared__ alignas(16) unsigned short Bs[2][128 * 32];
  __shared__ int toks[128];
  __shared__ float scl[128];
  __shared__ float bias_s[128];

  int tid = threadIdx.x;
  int lane = tid & 63;
  int w = tid >> 6;

  if (tid < 128) {
    int row = m0 + tid;
    int grow = row < count ? row : count - 1;  // clamp (valid addr, store-guarded)
    int tok = perm[(size_t)z * T + grow];
    toks[tid] = tok;
    scl[tid] = (row < count) ? scale[(size_t)r * T + tok] : 0.0f;
    bias_s[tid] = be[(size_t)z * HH + n0 + tid];
  }
  __syncthreads();

  // staging geometry: 512 x 8-float segments per tile; thread handles tid, tid+256
  const float* aptr[2];
  const float* bptr[2];
  int ldsoff[2];
#pragma unroll
  for (int i = 0; i < 2; ++i) {
    int linear = tid + i * 256;         // [0,512)
    int rowi = linear >> 2;             // 128 rows
    int segi = linear & 3;              // 4 x 8-element segments per row
    int tok = toks[rowi];
    aptr[i] = x + (size_t)(((tok >> 10) * 3 + r) * SS + (tok & 1023)) * HH +
              segi * 8;
    bptr[i] = We + ((size_t)z * HH + n0 + rowi) * HH + segi * 8;  // W[n][h]
    ldsoff[i] = rowi * 32 + segi * 8;
  }

  int wm = (w >> 1) * 64;
  int wn = (w & 1) * 64;
  floatx4 acc[4][4] = {};

  // prologue: load K-chunk 0
  float4 a0r[2], a1r[2], b0r[2], b1r[2];
#pragma unroll
  for (int i = 0; i < 2; ++i) {
    a0r[i] = reinterpret_cast<const float4*>(aptr[i])[0];
    a1r[i] = reinterpret_cast<const float4*>(aptr[i])[1];
    b0r[i] = reinterpret_cast<const float4*>(bptr[i])[0];
    b1r[i] = reinterpret_cast<const float4*>(bptr[i])[1];
  }

  for (int it = 0; it < 32; ++it) {
    int buf = it & 1;
    // pack fp32 regs -> bf16, write LDS[buf]
#pragma unroll
    for (int i = 0; i < 2; ++i) {
      uint4 av, bv;
      av.x = pack2(a0r[i].x, a0r[i].y); av.y = pack2(a0r[i].z, a0r[i].w);
      av.z = pack2(a1r[i].x, a1r[i].y); av.w = pack2(a1r[i].z, a1r[i].w);
      bv.x = pack2(b0r[i].x, b0r[i].y); bv.y = pack2(b0r[i].z, b0r[i].w);
      bv.z = pack2(b1r[i].x, b1r[i].y); bv.w = pack2(b1r[i].z, b1r[i].w);
      *reinterpret_cast<uint4*>(&As[buf][ldsoff[i]]) = av;
      *reinterpret_cast<uint4*>(&Bs[buf][ldsoff[i]]) = bv;
    }
    __syncthreads();  // LDS[buf] visible; also fences buf^1 reuse (2-iter gap)

    // software pipeline: issue next chunk's loads, overlapping MFMA below
    if (it < 31) {
      int kk = (it + 1) * 32;
#pragma unroll
      for (int i = 0; i < 2; ++i) {
        a0r[i] = reinterpret_cast<const float4*>(aptr[i] + kk)[0];
        a1r[i] = reinterpret_cast<const float4*>(aptr[i] + kk)[1];
        b0r[i] = reinterpret_cast<const float4*>(bptr[i] + kk)[0];
        b1r[i] = reinterpret_cast<const float4*>(bptr[i] + kk)[1];
      }
    }

    bf16x8 af[4], bq[4];
#pragma unroll
    for (int mt = 0; mt < 4; ++mt)
      af[mt] = *reinterpret_cast<const bf16x8*>(
          &As[buf][(wm + mt * 16 + (lane & 15)) * 32 + (lane >> 4) * 8]);
#pragma unroll
    for (int nt = 0; nt < 4; ++nt)
      bq[nt] = *reinterpret_cast<const bf16x8*>(
          &Bs[buf][(wn + nt * 16 + (lane & 15)) * 32 + (lane >> 4) * 8]);
#pragma unroll
    for (int mt = 0; mt < 4; ++mt)
#pragma unroll
      for (int nt = 0; nt < 4; ++nt)
        acc[mt][nt] = __builtin_amdgcn_mfma_f32_16x16x32_bf16(
            af[mt], bq[nt], acc[mt][nt], 0, 0, 0);
  }

  // epilogue: D row = (lane>>4)*4+reg, col = lane&15 (verified layout)
#pragma unroll
  for (int mt = 0; mt < 4; ++mt) {
#pragma unroll
    for (int rr = 0; rr < 4; ++rr) {
      int ml = wm + mt * 16 + (lane >> 4) * 4 + rr;
      if (m0 + ml < count) {
        float sc = scl[ml];
        int tok = toks[ml];
        size_t ob =
            (size_t)(((tok >> 10) * 3 + r) * SS + (tok & 1023)) * HH + n0;
#pragma unroll
        for (int nt = 0; nt < 4; ++nt) {
          int nl = wn + nt * 16 + (lane & 15);
          out[ob + nl] = sc * (acc[mt][nt][rr] + bias_s[nl]);
        }
      }
    }
  }
}

extern "C" void kernel_launch(void* const* d_in, const int* in_sizes, int n_in,
                              void* d_out, int out_size, void* d_ws,
                              size_t ws_size, hipStream_t stream) {
  const float* feat = (const float*)d_in[0];  // features fp32
  const float* gw   = (const float*)d_in[1];  // gate_w fp32
  const float* ew   = (const float*)d_in[2];  // expert_w fp32
  const float* eb   = (const float*)d_in[3];  // expert_b fp32
  float* out = (float*)d_out;

  int B = in_sizes[0] / (3 * SS * HH);
  int T = B * SS;                  // tokens per branch (8192)
  int C = (T + EE - 1) / EE;       // capacity = ceil(T/E) = 2731

  // workspace layout (ints/floats, 4B): ~576 KB total
  int* perm   = (int*)d_ws;                    // 9*T
  int* counts = perm + (size_t)9 * T;          // 16 (padded)
  int* idxb   = counts + 16;                   // 3*T
  float* gv   = (float*)(idxb + (size_t)3 * T);// 3*T
  float* scl  = gv + (size_t)3 * T;            // 3*T

  k_route<<<dim3(1536), dim3(256), 0, stream>>>(feat, gw, idxb, gv, T);
  k_scan<<<dim3(3), dim3(1024), 0, stream>>>(idxb, gv, perm, scl, counts, T, C);
  k_gemm<<<dim3((T + 127) / 128, HH / 128, 9), dim3(256), 0, stream>>>(
      feat, ew, eb, perm, scl, counts, out, T);
}

// Round 5
// 313.148 us; speedup vs baseline: 1.2572x; 1.2572x over previous
//
#include <hip/hip_runtime.h>
#include <math.h>

#define HH 1024
#define SS 1024
#define EE 3

typedef __bf16 bf16x8 __attribute__((ext_vector_type(8)));
typedef float floatx4 __attribute__((ext_vector_type(4)));

__device__ __forceinline__ unsigned short f2bf(float f) {
  union { float f; unsigned u; } v; v.f = f;
  unsigned r = 0x7FFFu + ((v.u >> 16) & 1u);
  return (unsigned short)((v.u + r) >> 16);
}
__device__ __forceinline__ unsigned pack2(float lo, float hi) {
#if __has_builtin(__builtin_amdgcn_cvt_pk_bf16_f32)
  auto p = __builtin_amdgcn_cvt_pk_bf16_f32(lo, hi);
  return __builtin_bit_cast(unsigned, p);
#else
  return ((unsigned)f2bf(hi) << 16) | (unsigned)f2bf(lo);
#endif
}

#define GLDS(gp, lp)                                                    \
  __builtin_amdgcn_global_load_lds(                                     \
      (const __attribute__((address_space(1))) void*)(const void*)(gp), \
      (__attribute__((address_space(3))) void*)(void*)(lp), 16, 0, 0)

// ---------- kernel 1: routing (argmax + gate) fused with x -> bf16 ----------
__global__ __launch_bounds__(256) void k_route(
    const float* __restrict__ x,          // [B,3,S,H] fp32
    const float* __restrict__ wg,         // [3,H,3]   fp32
    unsigned short* __restrict__ xb,      // [3,T,H] bf16 out
    int* __restrict__ idx_out,            // [3*T]
    float* __restrict__ gv_out,           // [3*T]
    int T) {
  int gw = (blockIdx.x * 256 + threadIdx.x) >> 6;  // global wave id [0,6144)
  int lane = threadIdx.x & 63;
  int r = gw >> 11;          // branch [0,3)
  int t0 = gw & 2047;        // starting token
  const float* w = wg + (size_t)r * HH * EE;

  // hoist this lane's gate slice: chunks c=0,1; h0 = c*512 + lane*8
  float wreg[2][24];
#pragma unroll
  for (int c = 0; c < 2; ++c) {
    int h0 = c * 512 + lane * 8;
    const float4* wp = reinterpret_cast<const float4*>(w + (size_t)h0 * 3);
#pragma unroll
    for (int j = 0; j < 6; ++j)
      *reinterpret_cast<float4*>(&wreg[c][4 * j]) = wp[j];
  }

  for (int t = t0; t < T; t += 2048) {
    const float* xrow =
        x + (size_t)(((t >> 10) * 3 + r) * SS + (t & 1023)) * HH;
    unsigned short* xbrow = xb + (size_t)(r * T + t) * HH;
    double a0 = 0, a1 = 0, a2 = 0;
#pragma unroll
    for (int c = 0; c < 2; ++c) {
      int h0 = c * 512 + lane * 8;
      float4 xa = *reinterpret_cast<const float4*>(xrow + h0);
      float4 xb4 = *reinterpret_cast<const float4*>(xrow + h0 + 4);
      float xs[8] = {xa.x, xa.y, xa.z, xa.w, xb4.x, xb4.y, xb4.z, xb4.w};
      // fused bf16 write-out (RNE, same as GEMM previously used)
      uint4 pk;
      pk.x = pack2(xs[0], xs[1]); pk.y = pack2(xs[2], xs[3]);
      pk.z = pack2(xs[4], xs[5]); pk.w = pack2(xs[6], xs[7]);
      *reinterpret_cast<uint4*>(xbrow + h0) = pk;
#pragma unroll
      for (int j = 0; j < 8; ++j) {
        double xv = (double)xs[j];
        a0 += xv * (double)wreg[c][3 * j + 0];
        a1 += xv * (double)wreg[c][3 * j + 1];
        a2 += xv * (double)wreg[c][3 * j + 2];
      }
    }
#pragma unroll
    for (int d = 32; d >= 1; d >>= 1) {
      a0 += __shfl_xor(a0, d, 64);
      a1 += __shfl_xor(a1, d, 64);
      a2 += __shfl_xor(a2, d, 64);
    }
    if (lane == 0) {
      int best = 0; double bl = a0;
      if (a1 > bl) { best = 1; bl = a1; }  // strict >: first-max wins
      if (a2 > bl) { best = 2; bl = a2; }
      float g = 1.0f / (expf((float)(a0 - bl)) + expf((float)(a1 - bl)) +
                        expf((float)(a2 - bl)));
      idx_out[r * T + t] = best;
      gv_out[r * T + t] = g;
    }
  }
}

// ---------------- kernel 1b: We fp32 -> bf16 ----------------
__global__ __launch_bounds__(256) void k_convw(
    const float* __restrict__ We, unsigned short* __restrict__ wb, int n8) {
  int i = blockIdx.x * 256 + threadIdx.x;  // one 8-elem segment per thread
  if (i >= n8) return;
  const float4* p = reinterpret_cast<const float4*>(We + (size_t)i * 8);
  float4 a = p[0], b = p[1];
  uint4 pk;
  pk.x = pack2(a.x, a.y); pk.y = pack2(a.z, a.w);
  pk.z = pack2(b.x, b.y); pk.w = pack2(b.z, b.w);
  *reinterpret_cast<uint4*>(wb + (size_t)i * 8) = pk;
}

// ---------------- kernel 2: arrival-order scan + expert lists ----------------
__global__ __launch_bounds__(1024) void k_scan(
    const int* __restrict__ idx, const float* __restrict__ gv,
    int* __restrict__ perm,    // [3*3*T] token ids per (branch,expert)
    float* __restrict__ scale, // [3*T]  gate*keep (0 if dropped)
    int* __restrict__ counts,  // [9]
    int T, int C) {
  int r = blockIdx.x;
  int tid = threadIdx.x;
  int per = T >> 10;  // tokens per thread (T=8192 -> 8)
  int t0 = tid * per;
  const int* idxr = idx + (size_t)r * T;

  int c0 = 0, c1 = 0, c2 = 0;
  for (int k = 0; k < per; ++k) {
    int e = idxr[t0 + k];
    c0 += (e == 0); c1 += (e == 1); c2 += (e == 2);
  }
  int lane = tid & 63, wv = tid >> 6;
  int s0 = c0, s1 = c1, s2 = c2;  // wave inclusive scan
  for (int d = 1; d < 64; d <<= 1) {
    int u0 = __shfl_up(s0, d, 64);
    int u1 = __shfl_up(s1, d, 64);
    int u2 = __shfl_up(s2, d, 64);
    if (lane >= d) { s0 += u0; s1 += u1; s2 += u2; }
  }
  __shared__ int wsum[16][3];
  __shared__ int wbase[16][3];
  if (lane == 63) { wsum[wv][0] = s0; wsum[wv][1] = s1; wsum[wv][2] = s2; }
  __syncthreads();
  if (tid == 0) {
    int b0 = 0, b1 = 0, b2 = 0;
    int nw = blockDim.x >> 6;
    for (int i = 0; i < nw; ++i) {
      wbase[i][0] = b0; wbase[i][1] = b1; wbase[i][2] = b2;
      b0 += wsum[i][0]; b1 += wsum[i][1]; b2 += wsum[i][2];
    }
    counts[r * 3 + 0] = b0; counts[r * 3 + 1] = b1; counts[r * 3 + 2] = b2;
  }
  __syncthreads();
  int off[3];
  off[0] = wbase[wv][0] + s0 - c0;
  off[1] = wbase[wv][1] + s1 - c1;
  off[2] = wbase[wv][2] + s2 - c2;
  for (int k = 0; k < per; ++k) {
    int e = idxr[t0 + k];
    int p = off[e]++;
    perm[(size_t)(r * 3 + e) * T + p] = t0 + k;
    scale[(size_t)r * T + t0 + k] = (p < C) ? gv[(size_t)r * T + t0 + k] : 0.0f;
  }
}

// ---------------- kernel 3: grouped GEMM, m97 structure ----------------
// bf16 inputs, 128x128 tile, BK=32, 4 waves, global_load_lds width=16,
// single-buffer LDS, 2 barriers/iter, mfma_f32_16x16x32_bf16, fp32 epilogue.
__global__ __launch_bounds__(256) void k_gemm(
    const unsigned short* __restrict__ xb,  // [3,T,H] bf16
    const unsigned short* __restrict__ wb,  // [3,3,H,H] bf16 (W[o][h])
    const float* __restrict__ be,           // [3,3,H] fp32
    const int* __restrict__ perm, const float* __restrict__ scale,
    const int* __restrict__ counts,
    float* __restrict__ out,                // [B,3,S,H] fp32
    int T) {
  int z = blockIdx.z;           // r*3+e
  int r = z / 3;
  int count = counts[z];
  int m0 = blockIdx.x * 128;    // m fast-varying -> B-slice L2 reuse
  if (m0 >= count) return;
  int n0 = blockIdx.y * 128;

  __shared__ alignas(16) unsigned short As[128 * 32];
  __shared__ alignas(16) unsigned short Bs[128 * 32];
  __shared__ int toks[128];
  __shared__ float scl[128];
  __shared__ float bias_s[128];

  int tid = threadIdx.x;
  int lane = tid & 63;
  int w = tid >> 6;

  if (tid < 128) {
    int row = m0 + tid;
    int grow = row < count ? row : count - 1;  // clamp (valid addr, store-guarded)
    int tok = perm[(size_t)z * T + grow];
    toks[tid] = tok;
    scl[tid] = (row < count) ? scale[(size_t)r * T + tok] : 0.0f;
    bias_s[tid] = be[(size_t)z * HH + n0 + tid];
  }
  __syncthreads();

  // staging: per wave, 2 GLDS for A + 2 for B; each covers 16 rows x 32 elems.
  // lane l stages 16B at LDS base + l*16 -> row base+(l>>2), seg (l&3)*8. Source
  // offsets must match that lane mapping exactly.
  size_t aoff[2], boff[2];
#pragma unroll
  for (int c = 0; c < 2; ++c) {
    int rowl = w * 32 + c * 16 + (lane >> 2);
    int tok = toks[rowl];
    aoff[c] = (size_t)(r * T + tok) * HH + (lane & 3) * 8;
    boff[c] = ((size_t)z * HH + n0 + rowl) * HH + (lane & 3) * 8;  // W[n][h]
  }

  int wm = (w >> 1) * 64;
  int wn = (w & 1) * 64;
  floatx4 acc[4][4] = {};

  for (int kk = 0; kk < HH; kk += 32) {
    __syncthreads();  // previous tile fully consumed by all waves
#pragma unroll
    for (int c = 0; c < 2; ++c) {
      GLDS(xb + aoff[c] + kk, &As[(w * 32 + c * 16) * 32]);
      GLDS(wb + boff[c] + kk, &Bs[(w * 32 + c * 16) * 32]);
    }
    __syncthreads();  // compiler emits vmcnt(0) before s_barrier -> LDS ready

    bf16x8 af[4], bq[4];
#pragma unroll
    for (int mt = 0; mt < 4; ++mt)
      af[mt] = *reinterpret_cast<const bf16x8*>(
          &As[(wm + mt * 16 + (lane & 15)) * 32 + (lane >> 4) * 8]);
#pragma unroll
    for (int nt = 0; nt < 4; ++nt)
      bq[nt] = *reinterpret_cast<const bf16x8*>(
          &Bs[(wn + nt * 16 + (lane & 15)) * 32 + (lane >> 4) * 8]);
#pragma unroll
    for (int mt = 0; mt < 4; ++mt)
#pragma unroll
      for (int nt = 0; nt < 4; ++nt)
        acc[mt][nt] = __builtin_amdgcn_mfma_f32_16x16x32_bf16(
            af[mt], bq[nt], acc[mt][nt], 0, 0, 0);
  }

  // epilogue: D row = (lane>>4)*4+reg, col = lane&15 (verified layout)
#pragma unroll
  for (int mt = 0; mt < 4; ++mt) {
#pragma unroll
    for (int rr = 0; rr < 4; ++rr) {
      int ml = wm + mt * 16 + (lane >> 4) * 4 + rr;
      if (m0 + ml < count) {
        float sc = scl[ml];
        int tok = toks[ml];
        size_t ob =
            (size_t)(((tok >> 10) * 3 + r) * SS + (tok & 1023)) * HH + n0;
#pragma unroll
        for (int nt = 0; nt < 4; ++nt) {
          int nl = wn + nt * 16 + (lane & 15);
          out[ob + nl] = sc * (acc[mt][nt][rr] + bias_s[nl]);
        }
      }
    }
  }
}

extern "C" void kernel_launch(void* const* d_in, const int* in_sizes, int n_in,
                              void* d_out, int out_size, void* d_ws,
                              size_t ws_size, hipStream_t stream) {
  const float* feat = (const float*)d_in[0];  // features fp32
  const float* gw   = (const float*)d_in[1];  // gate_w fp32
  const float* ew   = (const float*)d_in[2];  // expert_w fp32
  const float* eb   = (const float*)d_in[3];  // expert_b fp32
  float* out = (float*)d_out;

  int B = in_sizes[0] / (3 * SS * HH);
  int T = B * SS;                  // tokens per branch (8192)
  int C = (T + EE - 1) / EE;       // capacity = ceil(T/E) = 2731

  // workspace layout: xb bf16 [3,T,H] | wb bf16 [9,H,H] | ints/floats (~70 MB)
  unsigned short* xbuf = (unsigned short*)d_ws;           // 3*T*HH shorts
  unsigned short* wbuf = xbuf + (size_t)3 * T * HH;       // 9*HH*HH shorts
  int* perm   = (int*)(wbuf + (size_t)9 * HH * HH);       // 9*T
  int* counts = perm + (size_t)9 * T;                     // 16 (padded)
  int* idxb   = counts + 16;                              // 3*T
  float* gv   = (float*)(idxb + (size_t)3 * T);           // 3*T
  float* scl  = gv + (size_t)3 * T;                       // 3*T

  int n8 = 9 * HH * HH / 8;
  k_route<<<dim3(1536), dim3(256), 0, stream>>>(feat, gw, xbuf, idxb, gv, T);
  k_convw<<<dim3((n8 + 255) / 256), dim3(256), 0, stream>>>(ew, wbuf, n8);
  k_scan<<<dim3(3), dim3(1024), 0, stream>>>(idxb, gv, perm, scl, counts, T, C);
  k_gemm<<<dim3((T + 127) / 128, HH / 128, 9), dim3(256), 0, stream>>>(
      xbuf, wbuf, eb, perm, scl, counts, out, T);
}